// Round 11
// baseline (260.525 us; speedup 1.0000x reference)
//
#include <hip/hip_runtime.h>
#include <hip/hip_bf16.h>
#include <math.h>

constexpr int NB   = 4;
constexpr int LL   = 8192;
constexpr int DD   = 256;
constexpr int NH   = 8;
constexpr int HDIM = 32;
constexpr int WNN  = 9;
constexpr int PPAD = 4;

constexpr int CW  = 32;         // windows per attention block
constexpr int RSN = CW + 8;     // 40 staged rows
constexpr int SST = 260;        // bf16 LDS row stride (65 8B-slots, odd -> row spread)

typedef __attribute__((ext_vector_type(8))) short bf16x8;
typedef __attribute__((ext_vector_type(4))) float f32x4;

__device__ inline short f2bf(float f) {
  __hip_bfloat16 h = __float2bfloat16(f);
  short s; __builtin_memcpy(&s, &h, 2); return s;
}
__device__ inline float bf2f(short s) {
  unsigned u = ((unsigned)(unsigned short)s) << 16;
  float f; __builtin_memcpy(&f, &u, 4); return f;
}

// ---------------- merged prep: prep_w (bx 0..4) | pos_proj (bx 5..31) ----------------
__global__ __launch_bounds__(256) void prep_all(
    const float* __restrict__ Wq, const float* __restrict__ Wk, const float* __restrict__ Wv,
    const float* __restrict__ Wo, const float* __restrict__ Wout,
    short* __restrict__ WqT, short* __restrict__ WkT, short* __restrict__ WvT,
    short* __restrict__ WoT, short* __restrict__ WoutB,
    const float* __restrict__ pos,
    short* __restrict__ PQb, short* __restrict__ PKb, short* __restrict__ PVb) {
  __shared__ float ps[256];
  const int t = threadIdx.x;
  const int bx = blockIdx.x;
  if (bx < 4) {
    const float* W = (bx == 0) ? Wq : (bx == 1) ? Wk : (bx == 2) ? Wv : Wo;
    short* T = (bx == 0) ? WqT : (bx == 1) ? WkT : (bx == 2) ? WvT : WoT;
    for (int k = 0; k < 256; k += 4) {
      short4 o;
      o.x = f2bf(W[(size_t)(k + 0) * 256 + t]);
      o.y = f2bf(W[(size_t)(k + 1) * 256 + t]);
      o.z = f2bf(W[(size_t)(k + 2) * 256 + t]);
      o.w = f2bf(W[(size_t)(k + 3) * 256 + t]);
      *(short4*)&T[(size_t)t * 256 + k] = o;
    }
  } else if (bx == 4) {
    for (int i = t; i < 16384; i += 256) {
      float4 v = *(const float4*)(Wout + (size_t)i * 4);
      short4 o; o.x = f2bf(v.x); o.y = f2bf(v.y); o.z = f2bf(v.z); o.w = f2bf(v.w);
      *(short4*)(WoutB + (size_t)i * 4) = o;
    }
  } else {
    const int idx = bx - 5;
    const int wrow = idx % WNN, wh = idx / WNN;
    const float* W = (wh == 0) ? Wq : (wh == 1) ? Wk : Wv;
    short* P = (wh == 0) ? PQb : (wh == 1) ? PKb : PVb;
    ps[t] = pos[wrow * 256 + t];
    __syncthreads();
    float a = 0.f;
    for (int d = 0; d < 256; ++d) a += ps[d] * W[(size_t)d * 256 + t];
    P[wrow * 256 + t] = f2bf(a);
  }
}

// ---------------- merged QKV projection: A staged in LDS once, 3 GEMMs ----------------
// R8->R9 proven: depth-1 global prefetch into the MFMA loop is latency-death;
// A staged in LDS (264-stride) fixed it. R11: M=64 -> M=32 tile. At M=64 the
// grid was 512 blocks = 2 blocks/CU = 8 waves/CU -- still latency-bound
// (dur ~4x roofline, MFMA busy ~3% of block lifetime). M=32 doubles the grid
// to 1024 = 4 blocks/CU = 16 waves/CU. acc[2][4] (32 AGPR) -> register demand
// DROPS (no 128-clamp risk). B weights L2-resident, per-block traffic same.
__global__ __launch_bounds__(256) void qkv_mfma(
    const float* __restrict__ X,
    const short* __restrict__ WT0, const short* __restrict__ WT1, const short* __restrict__ WT2,
    short* __restrict__ O0, short* __restrict__ O1, short* __restrict__ O2) {
  __shared__ short ax[32 * 264];
  const int t = threadIdx.x, w = t >> 6, lane = t & 63, q = lane >> 4, m = lane & 15;
  const size_t row0 = (size_t)blockIdx.x * 32;

#pragma unroll
  for (int i = 0; i < 8; ++i) {
    int idx = (i * 256 + t) * 4;        // flat f32 index in tile (32x256)
    int row = idx >> 8, col = idx & 255;
    float4 v = *(const float4*)(X + (row0 + row) * (size_t)256 + col);
    short4 o; o.x = f2bf(v.x); o.y = f2bf(v.y); o.z = f2bf(v.z); o.w = f2bf(v.w);
    *(short4*)&ax[row * 264 + col] = o;
  }
  __syncthreads();

#pragma unroll 1
  for (int p = 0; p < 3; ++p) {
    const short* WT = (p == 0) ? WT0 : (p == 1) ? WT1 : WT2;
    short* O = (p == 0) ? O0 : (p == 1) ? O1 : O2;

    f32x4 acc[2][4];
#pragma unroll
    for (int i = 0; i < 2; ++i)
#pragma unroll
      for (int j = 0; j < 4; ++j) acc[i][j] = (f32x4){0.f, 0.f, 0.f, 0.f};

    const short* bbase = WT + (size_t)(w * 64 + m) * 256 + q * 8;
    bf16x8 b[4];
#pragma unroll
    for (int j = 0; j < 4; ++j) b[j] = *(const bf16x8*)(bbase + (size_t)j * 4096);
#pragma unroll
    for (int kk = 0; kk < 8; ++kk) {
      bf16x8 bn[4];
      if (kk < 7) {
#pragma unroll
        for (int j = 0; j < 4; ++j) bn[j] = *(const bf16x8*)(bbase + (size_t)j * 4096 + (kk + 1) * 32);
      }
      bf16x8 a[2];
#pragma unroll
      for (int i = 0; i < 2; ++i) a[i] = *(const bf16x8*)&ax[(i * 16 + m) * 264 + kk * 32 + q * 8];
#pragma unroll
      for (int i = 0; i < 2; ++i)
#pragma unroll
        for (int j = 0; j < 4; ++j)
          acc[i][j] = __builtin_amdgcn_mfma_f32_16x16x32_bf16(a[i], b[j], acc[i][j], 0, 0, 0);
      if (kk < 7) {
#pragma unroll
        for (int j = 0; j < 4; ++j) b[j] = bn[j];
      }
    }
#pragma unroll
    for (int i = 0; i < 2; ++i)
#pragma unroll
      for (int j = 0; j < 4; ++j)
#pragma unroll
        for (int r = 0; r < 4; ++r) {
          size_t row = row0 + i * 16 + q * 4 + r;
          int col = w * 64 + j * 16 + m;
          O[row * 256 + col] = f2bf(acc[i][j][r]);
        }
  }
}

// ---------------- windowed attention (R6/R1 kernel, EXACT) ----------------
// HISTORY: this structure = VGPR 120, FETCH 31 MB, no spill (R1/R6/R9/R10).
// Every restructure (R2-R5 LDS overlay; R7 512-thread row-split) pushed
// natural register demand into the 129-150 band; the allocator clamps to the
// 128 occupancy step and spills sc[] IN-LOOP (~850 MB/dispatch scratch).
// DO NOT restructure this loop's register layout.
// SQ_LDS_BANK_CONFLICT = 3538944 = structural ds_read_b64 floor. Closed axis.
__global__ __launch_bounds__(256, 2) void attn_kernel(
    const short* __restrict__ XQb, const short* __restrict__ XKb, const short* __restrict__ XVb,
    const short* __restrict__ PQb, const short* __restrict__ PKb, const short* __restrict__ PVb,
    short* __restrict__ CTXB) {
  __shared__ short sq[RSN * SST];
  __shared__ short sk[RSN * SST];
  __shared__ short sv[RSN * SST];
  __shared__ short pq[WNN * SST];
  __shared__ short pk[WNN * SST];
  __shared__ short pv[WNN * SST];

  const int t = threadIdx.x;
  const int nblk = LL / CW;
  const int b = blockIdx.x / nblk;
  const int n0 = (blockIdx.x % nblk) * CW;
  const size_t base = (size_t)b * LL * DD;

  const int lq   = t & 63;
  const int gcol = ((((lq & 7) << 3) | (lq >> 3))) * 4;   // global short offset of this lane's short4
  const int pcol = ((lq >> 3) << 5) | ((lq & 7) << 2);    // physical LDS short offset

#pragma unroll
  for (int i = 0; i < RSN / 4; ++i) {   // 10 iters, one full row per wave
    int r = (t >> 6) + i * 4;
    int j = n0 - PPAD + r;
    short4 vq = {0, 0, 0, 0}, vk = vq, vv = vq;
    if (j >= 0 && j < LL) {
      size_t off = base + (size_t)j * DD + gcol;
      vq = *(const short4*)(XQb + off);
      vk = *(const short4*)(XKb + off);
      vv = *(const short4*)(XVb + off);
    }
    *(short4*)&sq[r * SST + pcol] = vq;
    *(short4*)&sk[r * SST + pcol] = vk;
    *(short4*)&sv[r * SST + pcol] = vv;
  }
#pragma unroll
  for (int i = 0; i < 3; ++i) {
    int r = (t >> 6) + i * 4;
    if (r < WNN) {
      *(short4*)&pq[r * SST + pcol] = *(const short4*)(PQb + r * DD + gcol);
      *(short4*)&pk[r * SST + pcol] = *(const short4*)(PKb + r * DD + gcol);
      *(short4*)&pv[r * SST + pcol] = *(const short4*)(PVb + r * DD + gcol);
    }
  }
  __syncthreads();

  const int n = t >> 3;        // window within block
  const int h = t & 7;         // head
  const int hoff = h * HDIM;   // logical head offset (used for global writes only)
  const int hph = h * 4;       // physical head offset within a 32-short chunk

  float sc[WNN][WNN];
#pragma unroll
  for (int qi = 0; qi < WNN; ++qi)
#pragma unroll
    for (int ki = 0; ki < WNN; ++ki) sc[qi][ki] = 0.f;

#pragma unroll
  for (int c = 0; c < 8; ++c) {
    const int cph = c * 32 + hph;
    float qv[WNN][4], kv[WNN][4];
#pragma unroll
    for (int r = 0; r < WNN; ++r) {
      short4 xa = *(const short4*)&sq[(n + r) * SST + cph];
      short4 pa = *(const short4*)&pq[r * SST + cph];
      qv[r][0] = bf2f(xa.x) + bf2f(pa.x);
      qv[r][1] = bf2f(xa.y) + bf2f(pa.y);
      qv[r][2] = bf2f(xa.z) + bf2f(pa.z);
      qv[r][3] = bf2f(xa.w) + bf2f(pa.w);
      short4 xb = *(const short4*)&sk[(n + r) * SST + cph];
      short4 pb = *(const short4*)&pk[r * SST + cph];
      kv[r][0] = bf2f(xb.x) + bf2f(pb.x);
      kv[r][1] = bf2f(xb.y) + bf2f(pb.y);
      kv[r][2] = bf2f(xb.z) + bf2f(pb.z);
      kv[r][3] = bf2f(xb.w) + bf2f(pb.w);
    }
#pragma unroll
    for (int qi = 0; qi < WNN; ++qi)
#pragma unroll
      for (int ki = 0; ki < WNN; ++ki)
        sc[qi][ki] += qv[qi][0] * kv[ki][0] + qv[qi][1] * kv[ki][1] +
                      qv[qi][2] * kv[ki][2] + qv[qi][3] * kv[ki][3];
  }

  float cs[WNN];
#pragma unroll
  for (int ki = 0; ki < WNN; ++ki) cs[ki] = 0.f;
  const float scale = 0.17677669529663687f;  // 1/sqrt(32)
#pragma unroll
  for (int qi = 0; qi < WNN; ++qi) {
    float mx = sc[qi][0];
#pragma unroll
    for (int ki = 1; ki < WNN; ++ki) mx = fmaxf(mx, sc[qi][ki]);
    float e[WNN], sum = 0.f;
#pragma unroll
    for (int ki = 0; ki < WNN; ++ki) { e[ki] = __expf((sc[qi][ki] - mx) * scale); sum += e[ki]; }
    float inv = 1.f / sum;
#pragma unroll
    for (int ki = 0; ki < WNN; ++ki) cs[ki] += e[ki] * inv;
  }

#pragma unroll
  for (int c = 0; c < 8; ++c) {
    const int cph = c * 32 + hph;
    float o0 = 0.f, o1 = 0.f, o2 = 0.f, o3 = 0.f;
#pragma unroll
    for (int ki = 0; ki < WNN; ++ki) {
      short4 xv4 = *(const short4*)&sv[(n + ki) * SST + cph];
      short4 pv4 = *(const short4*)&pv[ki * SST + cph];
      float wt = cs[ki];
      o0 += wt * (bf2f(xv4.x) + bf2f(pv4.x));
      o1 += wt * (bf2f(xv4.y) + bf2f(pv4.y));
      o2 += wt * (bf2f(xv4.z) + bf2f(pv4.z));
      o3 += wt * (bf2f(xv4.w) + bf2f(pv4.w));
    }
    short4 os; os.x = f2bf(o0); os.y = f2bf(o1); os.z = f2bf(o2); os.w = f2bf(o3);
    *(short4*)(CTXB + base + (size_t)(n0 + n) * DD + hoff + c * 4) = os;
  }
}

// CAUTION: softmax scale note — reference scales scores BEFORE softmax; we fold
// the scale into the exp argument ((sc-mx)*scale) which is equivalent since mx
// is the max of unscaled scores and scale>0.

// ---------------- fused out stage via MFMA (M=32 tile, R11) ----------------
// Same occupancy fix as qkv: M=64 had 512 blocks = 2 blocks/CU; M=32 gives
// 1024 = 4 blocks/CU = 16 waves/CU. acc[2][4], ar[32*264] (16.9 KB), stats
// arrays 32 rows. A staged in LDS (R10); all loops mechanically halved.
__global__ __launch_bounds__(256) void out_mfma(
    const short* __restrict__ CTXB, const float* __restrict__ X,
    const short* __restrict__ WoT, const short* __restrict__ WoutB,
    const float* __restrict__ bo,
    const float* __restrict__ g1, const float* __restrict__ b1,
    const float* __restrict__ g2, const float* __restrict__ b2,
    float* __restrict__ out) {
  __shared__ short ar[32 * 264];
  __shared__ float ws1[32][4], ws2[32][4];
  __shared__ float msh[32], rsh[32];
  __shared__ float g1s[256], b1s[256], g2s[256], b2s[256], bos[256];
  const int t = threadIdx.x, w = t >> 6, lane = t & 63, q = lane >> 4, m = lane & 15;
  const size_t row0 = (size_t)blockIdx.x * 32;
  g1s[t] = g1[t]; b1s[t] = b1[t]; g2s[t] = g2[t]; b2s[t] = b2[t]; bos[t] = bo[t];

  // stage CTXB tile into ar (32 rows x 256 cols bf16)
#pragma unroll
  for (int i = 0; i < 8; ++i) {
    int idx = (i * 256 + t) * 4;        // flat short index in tile
    int row = idx >> 8, col = idx & 255;
    *(short4*)&ar[row * 264 + col] = *(const short4*)(CTXB + (row0 + row) * (size_t)256 + col);
  }
  __syncthreads();

  f32x4 acc[2][4];
#pragma unroll
  for (int i = 0; i < 2; ++i)
#pragma unroll
    for (int j = 0; j < 4; ++j) acc[i][j] = (f32x4){0.f, 0.f, 0.f, 0.f};

  // GEMM1: ctx @ Wo (A from LDS, B global with register-dbuf prefetch)
  const short* bbase = WoT + (size_t)(w * 64 + m) * 256 + q * 8;
  {
    bf16x8 b[4];
#pragma unroll
    for (int j = 0; j < 4; ++j) b[j] = *(const bf16x8*)(bbase + (size_t)j * 4096);
#pragma unroll
    for (int kk = 0; kk < 8; ++kk) {
      bf16x8 bn[4];
      if (kk < 7) {
#pragma unroll
        for (int j = 0; j < 4; ++j) bn[j] = *(const bf16x8*)(bbase + (size_t)j * 4096 + (kk + 1) * 32);
      }
      bf16x8 a[2];
#pragma unroll
      for (int i = 0; i < 2; ++i) a[i] = *(const bf16x8*)&ar[(i * 16 + m) * 264 + kk * 32 + q * 8];
#pragma unroll
      for (int i = 0; i < 2; ++i)
#pragma unroll
        for (int j = 0; j < 4; ++j)
          acc[i][j] = __builtin_amdgcn_mfma_f32_16x16x32_bf16(a[i], b[j], acc[i][j], 0, 0, 0);
      if (kk < 7) {
#pragma unroll
        for (int j = 0; j < 4; ++j) b[j] = bn[j];
      }
    }
  }

  // + skip, LN1 partial stats
  float s1v[2][4], s2v[2][4];
#pragma unroll
  for (int i = 0; i < 2; ++i)
#pragma unroll
    for (int r = 0; r < 4; ++r) {
      float a0 = 0.f, b0 = 0.f;
#pragma unroll
      for (int j = 0; j < 4; ++j) {
        float v = acc[i][j][r] + X[(row0 + i * 16 + q * 4 + r) * 256 + w * 64 + j * 16 + m];
        acc[i][j][r] = v; a0 += v; b0 += v * v;
      }
      s1v[i][r] = a0; s2v[i][r] = b0;
    }
#pragma unroll
  for (int i = 0; i < 2; ++i)
#pragma unroll
    for (int r = 0; r < 4; ++r)
#pragma unroll
      for (int msk = 1; msk < 16; msk <<= 1) {
        s1v[i][r] += __shfl_xor(s1v[i][r], msk, 64);
        s2v[i][r] += __shfl_xor(s2v[i][r], msk, 64);
      }
  if (m == 0) {
#pragma unroll
    for (int i = 0; i < 2; ++i)
#pragma unroll
      for (int r = 0; r < 4; ++r) {
        ws1[i * 16 + q * 4 + r][w] = s1v[i][r];
        ws2[i * 16 + q * 4 + r][w] = s2v[i][r];
      }
  }
  __syncthreads();
  if (t < 32) {
    float a0 = 0.f, b0 = 0.f;
#pragma unroll
    for (int ww = 0; ww < 4; ++ww) { a0 += ws1[t][ww]; b0 += ws2[t][ww]; }
    float mean = a0 * (1.f / 256.f);
    float var = b0 * (1.f / 256.f) - mean * mean;
    msh[t] = mean; rsh[t] = rsqrtf(var + 1e-5f);
  }
  __syncthreads();

#pragma unroll
  for (int i = 0; i < 2; ++i)
#pragma unroll
    for (int r = 0; r < 4; ++r) {
      int row = i * 16 + q * 4 + r;
      float mean = msh[row], rst = rsh[row];
#pragma unroll
      for (int j = 0; j < 4; ++j) {
        int col = w * 64 + j * 16 + m;
        float v = (acc[i][j][r] - mean) * rst * g1s[col] + b1s[col];
        ar[row * 264 + col] = f2bf(v);
      }
    }
  __syncthreads();

  // GEMM2: ar @ Wout^T (A from LDS, B global with prefetch)
#pragma unroll
  for (int i = 0; i < 2; ++i)
#pragma unroll
    for (int j = 0; j < 4; ++j) acc[i][j] = (f32x4){0.f, 0.f, 0.f, 0.f};
  const short* b2base = WoutB + (size_t)(w * 64 + m) * 256 + q * 8;
  {
    bf16x8 b[4];
#pragma unroll
    for (int j = 0; j < 4; ++j) b[j] = *(const bf16x8*)(b2base + (size_t)j * 4096);
#pragma unroll
    for (int kk = 0; kk < 8; ++kk) {
      bf16x8 bn[4];
      if (kk < 7) {
#pragma unroll
        for (int j = 0; j < 4; ++j) bn[j] = *(const bf16x8*)(b2base + (size_t)j * 4096 + (kk + 1) * 32);
      }
      bf16x8 a[2];
#pragma unroll
      for (int i = 0; i < 2; ++i) a[i] = *(const bf16x8*)&ar[(i * 16 + m) * 264 + kk * 32 + q * 8];
#pragma unroll
      for (int i = 0; i < 2; ++i)
#pragma unroll
        for (int j = 0; j < 4; ++j)
          acc[i][j] = __builtin_amdgcn_mfma_f32_16x16x32_bf16(a[i], b[j], acc[i][j], 0, 0, 0);
      if (kk < 7) {
#pragma unroll
        for (int j = 0; j < 4; ++j) b[j] = bn[j];
      }
    }
  }

  // + bias + residual, LN2 stats
#pragma unroll
  for (int i = 0; i < 2; ++i)
#pragma unroll
    for (int r = 0; r < 4; ++r) {
      int row = i * 16 + q * 4 + r;
      float a0 = 0.f, b0 = 0.f;
#pragma unroll
      for (int j = 0; j < 4; ++j) {
        int col = w * 64 + j * 16 + m;
        float v = acc[i][j][r] + bos[col] + bf2f(ar[row * 264 + col]);
        acc[i][j][r] = v; a0 += v; b0 += v * v;
      }
      s1v[i][r] = a0; s2v[i][r] = b0;
    }
#pragma unroll
  for (int i = 0; i < 2; ++i)
#pragma unroll
    for (int r = 0; r < 4; ++r)
#pragma unroll
      for (int msk = 1; msk < 16; msk <<= 1) {
        s1v[i][r] += __shfl_xor(s1v[i][r], msk, 64);
        s2v[i][r] += __shfl_xor(s2v[i][r], msk, 64);
      }
  if (m == 0) {
#pragma unroll
    for (int i = 0; i < 2; ++i)
#pragma unroll
      for (int r = 0; r < 4; ++r) {
        ws1[i * 16 + q * 4 + r][w] = s1v[i][r];
        ws2[i * 16 + q * 4 + r][w] = s2v[i][r];
      }
  }
  __syncthreads();
  if (t < 32) {
    float a0 = 0.f, b0 = 0.f;
#pragma unroll
    for (int ww = 0; ww < 4; ++ww) { a0 += ws1[t][ww]; b0 += ws2[t][ww]; }
    float mean = a0 * (1.f / 256.f);
    float var = b0 * (1.f / 256.f) - mean * mean;
    msh[t] = mean; rsh[t] = rsqrtf(var + 1e-5f);
  }
  __syncthreads();

#pragma unroll
  for (int i = 0; i < 2; ++i)
#pragma unroll
    for (int r = 0; r < 4; ++r) {
      int row = i * 16 + q * 4 + r;
      float mean = msh[row], rst = rsh[row];
#pragma unroll
      for (int j = 0; j < 4; ++j) {
        int col = w * 64 + j * 16 + m;
        float v = (acc[i][j][r] - mean) * rst * g2s[col] + b2s[col];
        out[(row0 + row) * 256 + col] = fmaxf(v, 0.f);
      }
    }
}

extern "C" void kernel_launch(void* const* d_in, const int* in_sizes, int n_in,
                              void* d_out, int out_size, void* d_ws, size_t ws_size,
                              hipStream_t stream) {
  const float* x    = (const float*)d_in[0];
  const float* Wq   = (const float*)d_in[1];
  const float* Wk   = (const float*)d_in[2];
  const float* Wv   = (const float*)d_in[3];
  const float* Wo   = (const float*)d_in[4];
  const float* pos  = (const float*)d_in[5];
  const float* Wout = (const float*)d_in[6];
  const float* bo   = (const float*)d_in[7];
  const float* g1   = (const float*)d_in[8];
  const float* b1   = (const float*)d_in[9];
  const float* g2   = (const float*)d_in[10];
  const float* b2   = (const float*)d_in[11];
  float* out = (float*)d_out;

  const size_t nel = (size_t)NB * LL * DD;
  char* wsb = (char*)d_ws;
  short* XQb  = (short*)wsb; wsb += nel * 2;
  short* XKb  = (short*)wsb; wsb += nel * 2;
  short* XVb  = (short*)wsb; wsb += nel * 2;
  short* CTXB = (short*)wsb; wsb += nel * 2;
  short* WqT   = (short*)wsb; wsb += 65536 * 2;
  short* WkT   = (short*)wsb; wsb += 65536 * 2;
  short* WvT   = (short*)wsb; wsb += 65536 * 2;
  short* WoT   = (short*)wsb; wsb += 65536 * 2;
  short* WoutB = (short*)wsb; wsb += 65536 * 2;
  short* PQb = (short*)wsb; wsb += WNN * DD * 2;
  short* PKb = (short*)wsb; wsb += WNN * DD * 2;
  short* PVb = (short*)wsb; wsb += WNN * DD * 2;

  prep_all<<<32, 256, 0, stream>>>(
      Wq, Wk, Wv, Wo, Wout, WqT, WkT, WvT, WoT, WoutB, pos, PQb, PKb, PVb);
  qkv_mfma<<<(unsigned)(NB * LL / 32), 256, 0, stream>>>(x, WqT, WkT, WvT, XQb, XKb, XVb);
  attn_kernel<<<NB * (LL / CW), 256, 0, stream>>>(XQb, XKb, XVb, PQb, PKb, PVb, CTXB);
  out_mfma<<<(unsigned)(NB * LL / 32), 256, 0, stream>>>(CTXB, x, WoT, WoutB, bo, g1, b1, g2, b2, out);
}

// Round 12
// 242.918 us; speedup vs baseline: 1.0725x; 1.0725x over previous
//
#include <hip/hip_runtime.h>
#include <hip/hip_bf16.h>
#include <math.h>

constexpr int NB   = 4;
constexpr int LL   = 8192;
constexpr int DD   = 256;
constexpr int NH   = 8;
constexpr int HDIM = 32;
constexpr int WNN  = 9;
constexpr int PPAD = 4;

constexpr int CW  = 32;         // windows per attention block
constexpr int RSN = CW + 8;     // 40 staged rows
constexpr int SST = 260;        // bf16 LDS row stride (65 8B-slots, odd -> row spread)

typedef __attribute__((ext_vector_type(8))) short bf16x8;
typedef __attribute__((ext_vector_type(4))) float f32x4;

__device__ inline short f2bf(float f) {
  __hip_bfloat16 h = __float2bfloat16(f);
  short s; __builtin_memcpy(&s, &h, 2); return s;
}
__device__ inline float bf2f(short s) {
  unsigned u = ((unsigned)(unsigned short)s) << 16;
  float f; __builtin_memcpy(&f, &u, 4); return f;
}

// ---------------- merged prep: prep_w (bx 0..4) | pos_proj (bx 5..31) ----------------
__global__ __launch_bounds__(256) void prep_all(
    const float* __restrict__ Wq, const float* __restrict__ Wk, const float* __restrict__ Wv,
    const float* __restrict__ Wo, const float* __restrict__ Wout,
    short* __restrict__ WqT, short* __restrict__ WkT, short* __restrict__ WvT,
    short* __restrict__ WoT, short* __restrict__ WoutB,
    const float* __restrict__ pos,
    short* __restrict__ PQb, short* __restrict__ PKb, short* __restrict__ PVb) {
  __shared__ float ps[256];
  const int t = threadIdx.x;
  const int bx = blockIdx.x;
  if (bx < 4) {
    const float* W = (bx == 0) ? Wq : (bx == 1) ? Wk : (bx == 2) ? Wv : Wo;
    short* T = (bx == 0) ? WqT : (bx == 1) ? WkT : (bx == 2) ? WvT : WoT;
    for (int k = 0; k < 256; k += 4) {
      short4 o;
      o.x = f2bf(W[(size_t)(k + 0) * 256 + t]);
      o.y = f2bf(W[(size_t)(k + 1) * 256 + t]);
      o.z = f2bf(W[(size_t)(k + 2) * 256 + t]);
      o.w = f2bf(W[(size_t)(k + 3) * 256 + t]);
      *(short4*)&T[(size_t)t * 256 + k] = o;
    }
  } else if (bx == 4) {
    for (int i = t; i < 16384; i += 256) {
      float4 v = *(const float4*)(Wout + (size_t)i * 4);
      short4 o; o.x = f2bf(v.x); o.y = f2bf(v.y); o.z = f2bf(v.z); o.w = f2bf(v.w);
      *(short4*)(WoutB + (size_t)i * 4) = o;
    }
  } else {
    const int idx = bx - 5;
    const int wrow = idx % WNN, wh = idx / WNN;
    const float* W = (wh == 0) ? Wq : (wh == 1) ? Wk : Wv;
    short* P = (wh == 0) ? PQb : (wh == 1) ? PKb : PVb;
    ps[t] = pos[wrow * 256 + t];
    __syncthreads();
    float a = 0.f;
    for (int d = 0; d < 256; ++d) a += ps[d] * W[(size_t)d * 256 + t];
    P[wrow * 256 + t] = f2bf(a);
  }
}

// ---------------- merged QKV projection: M=64 (R10 shape) + depth-2 B prefetch ----------------
// TILE HISTORY: M=64 merged (R9/R10) ~57us beats both M=64 split (R8, 78us)
// and M=32 merged (R11, 67us) -- per-block work amortization beats TLP for
// this latency-bound GEMM; the M-tile-down axis is CLOSED.
// R12: the k-loop critical path is the depth-1 B prefetch (~200-500cy L2
// latency vs ~80cy MFMA per step; MfmaUtil 7%, VALUBusy 5%, HBM 13% = all
// idle). Depth-2 rotating b[3][4] keeps 2 B-loads in flight (+16 VGPR, 80->
// ~96, far from the 128 clamp). All b[] indices compile-time after unroll.
__global__ __launch_bounds__(256) void qkv_mfma(
    const float* __restrict__ X,
    const short* __restrict__ WT0, const short* __restrict__ WT1, const short* __restrict__ WT2,
    short* __restrict__ O0, short* __restrict__ O1, short* __restrict__ O2) {
  __shared__ short ax[64 * 264];
  const int t = threadIdx.x, w = t >> 6, lane = t & 63, q = lane >> 4, m = lane & 15;
  const size_t row0 = (size_t)blockIdx.x * 64;

#pragma unroll
  for (int i = 0; i < 16; ++i) {
    int idx = (i * 256 + t) * 4;        // flat f32 index in tile
    int row = idx >> 8, col = idx & 255;
    float4 v = *(const float4*)(X + (row0 + row) * (size_t)256 + col);
    short4 o; o.x = f2bf(v.x); o.y = f2bf(v.y); o.z = f2bf(v.z); o.w = f2bf(v.w);
    *(short4*)&ax[row * 264 + col] = o;
  }
  __syncthreads();

#pragma unroll 1
  for (int p = 0; p < 3; ++p) {
    const short* WT = (p == 0) ? WT0 : (p == 1) ? WT1 : WT2;
    short* O = (p == 0) ? O0 : (p == 1) ? O1 : O2;

    f32x4 acc[4][4];
#pragma unroll
    for (int i = 0; i < 4; ++i)
#pragma unroll
      for (int j = 0; j < 4; ++j) acc[i][j] = (f32x4){0.f, 0.f, 0.f, 0.f};

    const short* bbase = WT + (size_t)(w * 64 + m) * 256 + q * 8;
    bf16x8 b[3][4];
#pragma unroll
    for (int j = 0; j < 4; ++j) b[0][j] = *(const bf16x8*)(bbase + (size_t)j * 4096);
#pragma unroll
    for (int j = 0; j < 4; ++j) b[1][j] = *(const bf16x8*)(bbase + (size_t)j * 4096 + 32);
#pragma unroll
    for (int kk = 0; kk < 8; ++kk) {
      if (kk < 6) {
#pragma unroll
        for (int j = 0; j < 4; ++j)
          b[(kk + 2) % 3][j] = *(const bf16x8*)(bbase + (size_t)j * 4096 + (kk + 2) * 32);
      }
      bf16x8 a[4];
#pragma unroll
      for (int i = 0; i < 4; ++i) a[i] = *(const bf16x8*)&ax[(i * 16 + m) * 264 + kk * 32 + q * 8];
#pragma unroll
      for (int i = 0; i < 4; ++i)
#pragma unroll
        for (int j = 0; j < 4; ++j)
          acc[i][j] = __builtin_amdgcn_mfma_f32_16x16x32_bf16(a[i], b[kk % 3][j], acc[i][j], 0, 0, 0);
    }
#pragma unroll
    for (int i = 0; i < 4; ++i)
#pragma unroll
      for (int j = 0; j < 4; ++j)
#pragma unroll
        for (int r = 0; r < 4; ++r) {
          size_t row = row0 + i * 16 + q * 4 + r;
          int col = w * 64 + j * 16 + m;
          O[row * 256 + col] = f2bf(acc[i][j][r]);
        }
  }
}

// ---------------- windowed attention (R6/R1 kernel, EXACT) ----------------
// HISTORY: this structure = VGPR 120, FETCH 31 MB, no spill (R1/R6/R9/R10).
// Every restructure (R2-R5 LDS overlay; R7 512-thread row-split) pushed
// natural register demand into the 129-150 band; the allocator clamps to the
// 128 occupancy step and spills sc[] IN-LOOP (~850 MB/dispatch scratch).
// DO NOT restructure this loop's register layout.
// SQ_LDS_BANK_CONFLICT = 3538944 = structural ds_read_b64 floor. Closed axis.
__global__ __launch_bounds__(256, 2) void attn_kernel(
    const short* __restrict__ XQb, const short* __restrict__ XKb, const short* __restrict__ XVb,
    const short* __restrict__ PQb, const short* __restrict__ PKb, const short* __restrict__ PVb,
    short* __restrict__ CTXB) {
  __shared__ short sq[RSN * SST];
  __shared__ short sk[RSN * SST];
  __shared__ short sv[RSN * SST];
  __shared__ short pq[WNN * SST];
  __shared__ short pk[WNN * SST];
  __shared__ short pv[WNN * SST];

  const int t = threadIdx.x;
  const int nblk = LL / CW;
  const int b = blockIdx.x / nblk;
  const int n0 = (blockIdx.x % nblk) * CW;
  const size_t base = (size_t)b * LL * DD;

  const int lq   = t & 63;
  const int gcol = ((((lq & 7) << 3) | (lq >> 3))) * 4;   // global short offset of this lane's short4
  const int pcol = ((lq >> 3) << 5) | ((lq & 7) << 2);    // physical LDS short offset

#pragma unroll
  for (int i = 0; i < RSN / 4; ++i) {   // 10 iters, one full row per wave
    int r = (t >> 6) + i * 4;
    int j = n0 - PPAD + r;
    short4 vq = {0, 0, 0, 0}, vk = vq, vv = vq;
    if (j >= 0 && j < LL) {
      size_t off = base + (size_t)j * DD + gcol;
      vq = *(const short4*)(XQb + off);
      vk = *(const short4*)(XKb + off);
      vv = *(const short4*)(XVb + off);
    }
    *(short4*)&sq[r * SST + pcol] = vq;
    *(short4*)&sk[r * SST + pcol] = vk;
    *(short4*)&sv[r * SST + pcol] = vv;
  }
#pragma unroll
  for (int i = 0; i < 3; ++i) {
    int r = (t >> 6) + i * 4;
    if (r < WNN) {
      *(short4*)&pq[r * SST + pcol] = *(const short4*)(PQb + r * DD + gcol);
      *(short4*)&pk[r * SST + pcol] = *(const short4*)(PKb + r * DD + gcol);
      *(short4*)&pv[r * SST + pcol] = *(const short4*)(PVb + r * DD + gcol);
    }
  }
  __syncthreads();

  const int n = t >> 3;        // window within block
  const int h = t & 7;         // head
  const int hoff = h * HDIM;   // logical head offset (used for global writes only)
  const int hph = h * 4;       // physical head offset within a 32-short chunk

  float sc[WNN][WNN];
#pragma unroll
  for (int qi = 0; qi < WNN; ++qi)
#pragma unroll
    for (int ki = 0; ki < WNN; ++ki) sc[qi][ki] = 0.f;

#pragma unroll
  for (int c = 0; c < 8; ++c) {
    const int cph = c * 32 + hph;
    float qv[WNN][4], kv[WNN][4];
#pragma unroll
    for (int r = 0; r < WNN; ++r) {
      short4 xa = *(const short4*)&sq[(n + r) * SST + cph];
      short4 pa = *(const short4*)&pq[r * SST + cph];
      qv[r][0] = bf2f(xa.x) + bf2f(pa.x);
      qv[r][1] = bf2f(xa.y) + bf2f(pa.y);
      qv[r][2] = bf2f(xa.z) + bf2f(pa.z);
      qv[r][3] = bf2f(xa.w) + bf2f(pa.w);
      short4 xb = *(const short4*)&sk[(n + r) * SST + cph];
      short4 pb = *(const short4*)&pk[r * SST + cph];
      kv[r][0] = bf2f(xb.x) + bf2f(pb.x);
      kv[r][1] = bf2f(xb.y) + bf2f(pb.y);
      kv[r][2] = bf2f(xb.z) + bf2f(pb.z);
      kv[r][3] = bf2f(xb.w) + bf2f(pb.w);
    }
#pragma unroll
    for (int qi = 0; qi < WNN; ++qi)
#pragma unroll
      for (int ki = 0; ki < WNN; ++ki)
        sc[qi][ki] += qv[qi][0] * kv[ki][0] + qv[qi][1] * kv[ki][1] +
                      qv[qi][2] * kv[ki][2] + qv[qi][3] * kv[ki][3];
  }

  float cs[WNN];
#pragma unroll
  for (int ki = 0; ki < WNN; ++ki) cs[ki] = 0.f;
  const float scale = 0.17677669529663687f;  // 1/sqrt(32)
#pragma unroll
  for (int qi = 0; qi < WNN; ++qi) {
    float mx = sc[qi][0];
#pragma unroll
    for (int ki = 1; ki < WNN; ++ki) mx = fmaxf(mx, sc[qi][ki]);
    float e[WNN], sum = 0.f;
#pragma unroll
    for (int ki = 0; ki < WNN; ++ki) { e[ki] = __expf((sc[qi][ki] - mx) * scale); sum += e[ki]; }
    float inv = 1.f / sum;
#pragma unroll
    for (int ki = 0; ki < WNN; ++ki) cs[ki] += e[ki] * inv;
  }

#pragma unroll
  for (int c = 0; c < 8; ++c) {
    const int cph = c * 32 + hph;
    float o0 = 0.f, o1 = 0.f, o2 = 0.f, o3 = 0.f;
#pragma unroll
    for (int ki = 0; ki < WNN; ++ki) {
      short4 xv4 = *(const short4*)&sv[(n + ki) * SST + cph];
      short4 pv4 = *(const short4*)&pv[ki * SST + cph];
      float wt = cs[ki];
      o0 += wt * (bf2f(xv4.x) + bf2f(pv4.x));
      o1 += wt * (bf2f(xv4.y) + bf2f(pv4.y));
      o2 += wt * (bf2f(xv4.z) + bf2f(pv4.z));
      o3 += wt * (bf2f(xv4.w) + bf2f(pv4.w));
    }
    short4 os; os.x = f2bf(o0); os.y = f2bf(o1); os.z = f2bf(o2); os.w = f2bf(o3);
    *(short4*)(CTXB + base + (size_t)(n0 + n) * DD + hoff + c * 4) = os;
  }
}

// CAUTION: softmax scale note — reference scales scores BEFORE softmax; we fold
// the scale into the exp argument ((sc-mx)*scale) which is equivalent since mx
// is the max of unscaled scores and scale>0.

// ---------------- fused out stage via MFMA (M=64, R10 shape + depth-2 B prefetch) ----------------
__global__ __launch_bounds__(256) void out_mfma(
    const short* __restrict__ CTXB, const float* __restrict__ X,
    const short* __restrict__ WoT, const short* __restrict__ WoutB,
    const float* __restrict__ bo,
    const float* __restrict__ g1, const float* __restrict__ b1,
    const float* __restrict__ g2, const float* __restrict__ b2,
    float* __restrict__ out) {
  __shared__ short ar[64 * 264];
  __shared__ float ws1[64][4], ws2[64][4];
  __shared__ float msh[64], rsh[64];
  __shared__ float g1s[256], b1s[256], g2s[256], b2s[256], bos[256];
  const int t = threadIdx.x, w = t >> 6, lane = t & 63, q = lane >> 4, m = lane & 15;
  const size_t row0 = (size_t)blockIdx.x * 64;
  g1s[t] = g1[t]; b1s[t] = b1[t]; g2s[t] = g2[t]; b2s[t] = b2[t]; bos[t] = bo[t];

  // stage CTXB tile into ar (64 rows x 256 cols bf16)
#pragma unroll
  for (int i = 0; i < 16; ++i) {
    int idx = (i * 256 + t) * 4;        // flat short index in tile
    int row = idx >> 8, col = idx & 255;
    *(short4*)&ar[row * 264 + col] = *(const short4*)(CTXB + (row0 + row) * (size_t)256 + col);
  }
  __syncthreads();

  f32x4 acc[4][4];
#pragma unroll
  for (int i = 0; i < 4; ++i)
#pragma unroll
    for (int j = 0; j < 4; ++j) acc[i][j] = (f32x4){0.f, 0.f, 0.f, 0.f};

  // GEMM1: ctx @ Wo (A from LDS, B global with depth-2 rotating prefetch)
  const short* bbase = WoT + (size_t)(w * 64 + m) * 256 + q * 8;
  {
    bf16x8 b[3][4];
#pragma unroll
    for (int j = 0; j < 4; ++j) b[0][j] = *(const bf16x8*)(bbase + (size_t)j * 4096);
#pragma unroll
    for (int j = 0; j < 4; ++j) b[1][j] = *(const bf16x8*)(bbase + (size_t)j * 4096 + 32);
#pragma unroll
    for (int kk = 0; kk < 8; ++kk) {
      if (kk < 6) {
#pragma unroll
        for (int j = 0; j < 4; ++j)
          b[(kk + 2) % 3][j] = *(const bf16x8*)(bbase + (size_t)j * 4096 + (kk + 2) * 32);
      }
      bf16x8 a[4];
#pragma unroll
      for (int i = 0; i < 4; ++i) a[i] = *(const bf16x8*)&ar[(i * 16 + m) * 264 + kk * 32 + q * 8];
#pragma unroll
      for (int i = 0; i < 4; ++i)
#pragma unroll
        for (int j = 0; j < 4; ++j)
          acc[i][j] = __builtin_amdgcn_mfma_f32_16x16x32_bf16(a[i], b[kk % 3][j], acc[i][j], 0, 0, 0);
    }
  }

  // + skip, LN1 partial stats
  float s1v[4][4], s2v[4][4];
#pragma unroll
  for (int i = 0; i < 4; ++i)
#pragma unroll
    for (int r = 0; r < 4; ++r) {
      float a0 = 0.f, b0 = 0.f;
#pragma unroll
      for (int j = 0; j < 4; ++j) {
        float v = acc[i][j][r] + X[(row0 + i * 16 + q * 4 + r) * 256 + w * 64 + j * 16 + m];
        acc[i][j][r] = v; a0 += v; b0 += v * v;
      }
      s1v[i][r] = a0; s2v[i][r] = b0;
    }
#pragma unroll
  for (int i = 0; i < 4; ++i)
#pragma unroll
    for (int r = 0; r < 4; ++r)
#pragma unroll
      for (int msk = 1; msk < 16; msk <<= 1) {
        s1v[i][r] += __shfl_xor(s1v[i][r], msk, 64);
        s2v[i][r] += __shfl_xor(s2v[i][r], msk, 64);
      }
  if (m == 0) {
#pragma unroll
    for (int i = 0; i < 4; ++i)
#pragma unroll
      for (int r = 0; r < 4; ++r) {
        ws1[i * 16 + q * 4 + r][w] = s1v[i][r];
        ws2[i * 16 + q * 4 + r][w] = s2v[i][r];
      }
  }
  __syncthreads();
  if (t < 64) {
    float a0 = 0.f, b0 = 0.f;
#pragma unroll
    for (int ww = 0; ww < 4; ++ww) { a0 += ws1[t][ww]; b0 += ws2[t][ww]; }
    float mean = a0 * (1.f / 256.f);
    float var = b0 * (1.f / 256.f) - mean * mean;
    msh[t] = mean; rsh[t] = rsqrtf(var + 1e-5f);
  }
  __syncthreads();

#pragma unroll
  for (int i = 0; i < 4; ++i)
#pragma unroll
    for (int r = 0; r < 4; ++r) {
      int row = i * 16 + q * 4 + r;
      float mean = msh[row], rst = rsh[row];
#pragma unroll
      for (int j = 0; j < 4; ++j) {
        int col = w * 64 + j * 16 + m;
        float v = (acc[i][j][r] - mean) * rst * g1s[col] + b1s[col];
        ar[row * 264 + col] = f2bf(v);
      }
    }
  __syncthreads();

  // GEMM2: ar @ Wout^T (A from LDS, B global with depth-2 rotating prefetch)
#pragma unroll
  for (int i = 0; i < 4; ++i)
#pragma unroll
    for (int j = 0; j < 4; ++j) acc[i][j] = (f32x4){0.f, 0.f, 0.f, 0.f};
  const short* b2base = WoutB + (size_t)(w * 64 + m) * 256 + q * 8;
  {
    bf16x8 b[3][4];
#pragma unroll
    for (int j = 0; j < 4; ++j) b[0][j] = *(const bf16x8*)(b2base + (size_t)j * 4096);
#pragma unroll
    for (int j = 0; j < 4; ++j) b[1][j] = *(const bf16x8*)(b2base + (size_t)j * 4096 + 32);
#pragma unroll
    for (int kk = 0; kk < 8; ++kk) {
      if (kk < 6) {
#pragma unroll
        for (int j = 0; j < 4; ++j)
          b[(kk + 2) % 3][j] = *(const bf16x8*)(b2base + (size_t)j * 4096 + (kk + 2) * 32);
      }
      bf16x8 a[4];
#pragma unroll
      for (int i = 0; i < 4; ++i) a[i] = *(const bf16x8*)&ar[(i * 16 + m) * 264 + kk * 32 + q * 8];
#pragma unroll
      for (int i = 0; i < 4; ++i)
#pragma unroll
        for (int j = 0; j < 4; ++j)
          acc[i][j] = __builtin_amdgcn_mfma_f32_16x16x32_bf16(a[i], b[kk % 3][j], acc[i][j], 0, 0, 0);
    }
  }

  // + bias + residual, LN2 stats
#pragma unroll
  for (int i = 0; i < 4; ++i)
#pragma unroll
    for (int r = 0; r < 4; ++r) {
      int row = i * 16 + q * 4 + r;
      float a0 = 0.f, b0 = 0.f;
#pragma unroll
      for (int j = 0; j < 4; ++j) {
        int col = w * 64 + j * 16 + m;
        float v = acc[i][j][r] + bos[col] + bf2f(ar[row * 264 + col]);
        acc[i][j][r] = v; a0 += v; b0 += v * v;
      }
      s1v[i][r] = a0; s2v[i][r] = b0;
    }
#pragma unroll
  for (int i = 0; i < 4; ++i)
#pragma unroll
    for (int r = 0; r < 4; ++r)
#pragma unroll
      for (int msk = 1; msk < 16; msk <<= 1) {
        s1v[i][r] += __shfl_xor(s1v[i][r], msk, 64);
        s2v[i][r] += __shfl_xor(s2v[i][r], msk, 64);
      }
  if (m == 0) {
#pragma unroll
    for (int i = 0; i < 4; ++i)
#pragma unroll
      for (int r = 0; r < 4; ++r) {
        ws1[i * 16 + q * 4 + r][w] = s1v[i][r];
        ws2[i * 16 + q * 4 + r][w] = s2v[i][r];
      }
  }
  __syncthreads();
  if (t < 64) {
    float a0 = 0.f, b0 = 0.f;
#pragma unroll
    for (int ww = 0; ww < 4; ++ww) { a0 += ws1[t][ww]; b0 += ws2[t][ww]; }
    float mean = a0 * (1.f / 256.f);
    float var = b0 * (1.f / 256.f) - mean * mean;
    msh[t] = mean; rsh[t] = rsqrtf(var + 1e-5f);
  }
  __syncthreads();

#pragma unroll
  for (int i = 0; i < 4; ++i)
#pragma unroll
    for (int r = 0; r < 4; ++r) {
      int row = i * 16 + q * 4 + r;
      float mean = msh[row], rst = rsh[row];
#pragma unroll
      for (int j = 0; j < 4; ++j) {
        int col = w * 64 + j * 16 + m;
        float v = (acc[i][j][r] - mean) * rst * g2s[col] + b2s[col];
        out[(row0 + row) * 256 + col] = fmaxf(v, 0.f);
      }
    }
}

extern "C" void kernel_launch(void* const* d_in, const int* in_sizes, int n_in,
                              void* d_out, int out_size, void* d_ws, size_t ws_size,
                              hipStream_t stream) {
  const float* x    = (const float*)d_in[0];
  const float* Wq   = (const float*)d_in[1];
  const float* Wk   = (const float*)d_in[2];
  const float* Wv   = (const float*)d_in[3];
  const float* Wo   = (const float*)d_in[4];
  const float* pos  = (const float*)d_in[5];
  const float* Wout = (const float*)d_in[6];
  const float* bo   = (const float*)d_in[7];
  const float* g1   = (const float*)d_in[8];
  const float* b1   = (const float*)d_in[9];
  const float* g2   = (const float*)d_in[10];
  const float* b2   = (const float*)d_in[11];
  float* out = (float*)d_out;

  const size_t nel = (size_t)NB * LL * DD;
  char* wsb = (char*)d_ws;
  short* XQb  = (short*)wsb; wsb += nel * 2;
  short* XKb  = (short*)wsb; wsb += nel * 2;
  short* XVb  = (short*)wsb; wsb += nel * 2;
  short* CTXB = (short*)wsb; wsb += nel * 2;
  short* WqT   = (short*)wsb; wsb += 65536 * 2;
  short* WkT   = (short*)wsb; wsb += 65536 * 2;
  short* WvT   = (short*)wsb; wsb += 65536 * 2;
  short* WoT   = (short*)wsb; wsb += 65536 * 2;
  short* WoutB = (short*)wsb; wsb += 65536 * 2;
  short* PQb = (short*)wsb; wsb += WNN * DD * 2;
  short* PKb = (short*)wsb; wsb += WNN * DD * 2;
  short* PVb = (short*)wsb; wsb += WNN * DD * 2;

  prep_all<<<32, 256, 0, stream>>>(
      Wq, Wk, Wv, Wo, Wout, WqT, WkT, WvT, WoT, WoutB, pos, PQb, PKb, PVb);
  qkv_mfma<<<(unsigned)(NB * LL / 64), 256, 0, stream>>>(x, WqT, WkT, WvT, XQb, XKb, XVb);
  attn_kernel<<<NB * (LL / CW), 256, 0, stream>>>(XQb, XKb, XVb, PQb, PKb, PVb, CTXB);
  out_mfma<<<(unsigned)(NB * LL / 64), 256, 0, stream>>>(CTXB, x, WoT, WoutB, bo, g1, b1, g2, b2, out);
}

// Round 13
// 234.815 us; speedup vs baseline: 1.1095x; 1.0345x over previous
//
#include <hip/hip_runtime.h>
#include <hip/hip_bf16.h>
#include <math.h>

constexpr int NB   = 4;
constexpr int LL   = 8192;
constexpr int DD   = 256;
constexpr int NH   = 8;
constexpr int HDIM = 32;
constexpr int WNN  = 9;
constexpr int PPAD = 4;

constexpr int CW  = 32;         // windows per attention block
constexpr int RSN = CW + 8;     // 40 staged rows
constexpr int SST = 260;        // bf16 LDS row stride (65 8B-slots, odd -> row spread)

typedef __attribute__((ext_vector_type(8))) short bf16x8;
typedef __attribute__((ext_vector_type(4))) float f32x4;

__device__ inline short f2bf(float f) {
  __hip_bfloat16 h = __float2bfloat16(f);
  short s; __builtin_memcpy(&s, &h, 2); return s;
}
__device__ inline float bf2f(short s) {
  unsigned u = ((unsigned)(unsigned short)s) << 16;
  float f; __builtin_memcpy(&f, &u, 4); return f;
}

// ---------------- merged prep: prep_w (bx 0..4) | pos_proj (bx 5..31) ----------------
__global__ __launch_bounds__(256) void prep_all(
    const float* __restrict__ Wq, const float* __restrict__ Wk, const float* __restrict__ Wv,
    const float* __restrict__ Wo, const float* __restrict__ Wout,
    short* __restrict__ WqT, short* __restrict__ WkT, short* __restrict__ WvT,
    short* __restrict__ WoT, short* __restrict__ WoutB,
    const float* __restrict__ pos,
    short* __restrict__ PQb, short* __restrict__ PKb, short* __restrict__ PVb) {
  __shared__ float ps[256];
  const int t = threadIdx.x;
  const int bx = blockIdx.x;
  if (bx < 4) {
    const float* W = (bx == 0) ? Wq : (bx == 1) ? Wk : (bx == 2) ? Wv : Wo;
    short* T = (bx == 0) ? WqT : (bx == 1) ? WkT : (bx == 2) ? WvT : WoT;
    for (int k = 0; k < 256; k += 4) {
      short4 o;
      o.x = f2bf(W[(size_t)(k + 0) * 256 + t]);
      o.y = f2bf(W[(size_t)(k + 1) * 256 + t]);
      o.z = f2bf(W[(size_t)(k + 2) * 256 + t]);
      o.w = f2bf(W[(size_t)(k + 3) * 256 + t]);
      *(short4*)&T[(size_t)t * 256 + k] = o;
    }
  } else if (bx == 4) {
    for (int i = t; i < 16384; i += 256) {
      float4 v = *(const float4*)(Wout + (size_t)i * 4);
      short4 o; o.x = f2bf(v.x); o.y = f2bf(v.y); o.z = f2bf(v.z); o.w = f2bf(v.w);
      *(short4*)(WoutB + (size_t)i * 4) = o;
    }
  } else {
    const int idx = bx - 5;
    const int wrow = idx % WNN, wh = idx / WNN;
    const float* W = (wh == 0) ? Wq : (wh == 1) ? Wk : Wv;
    short* P = (wh == 0) ? PQb : (wh == 1) ? PKb : PVb;
    ps[t] = pos[wrow * 256 + t];
    __syncthreads();
    float a = 0.f;
    for (int d = 0; d < 256; ++d) a += ps[d] * W[(size_t)d * 256 + t];
    P[wrow * 256 + t] = f2bf(a);
  }
}

// ---------------- merged QKV projection: A staged in LDS once, 3 GEMMs (R10 exact) ----------------
// LEVER LEDGER (closed axes): split-grid (R8: 78us, MfmaUtil 6% latency-death);
// M=32 tile (R11: 67us, amortization loss); depth-2 B prefetch (R12: neutral,
// compiler re-schedules). M=64 merged + A-from-LDS + depth-1 = verified best.
__global__ __launch_bounds__(256) void qkv_mfma(
    const float* __restrict__ X,
    const short* __restrict__ WT0, const short* __restrict__ WT1, const short* __restrict__ WT2,
    short* __restrict__ O0, short* __restrict__ O1, short* __restrict__ O2) {
  __shared__ short ax[64 * 264];
  const int t = threadIdx.x, w = t >> 6, lane = t & 63, q = lane >> 4, m = lane & 15;
  const size_t row0 = (size_t)blockIdx.x * 64;

#pragma unroll
  for (int i = 0; i < 16; ++i) {
    int idx = (i * 256 + t) * 4;        // flat f32 index in tile
    int row = idx >> 8, col = idx & 255;
    float4 v = *(const float4*)(X + (row0 + row) * (size_t)256 + col);
    short4 o; o.x = f2bf(v.x); o.y = f2bf(v.y); o.z = f2bf(v.z); o.w = f2bf(v.w);
    *(short4*)&ax[row * 264 + col] = o;
  }
  __syncthreads();

#pragma unroll 1
  for (int p = 0; p < 3; ++p) {
    const short* WT = (p == 0) ? WT0 : (p == 1) ? WT1 : WT2;
    short* O = (p == 0) ? O0 : (p == 1) ? O1 : O2;

    f32x4 acc[4][4];
#pragma unroll
    for (int i = 0; i < 4; ++i)
#pragma unroll
      for (int j = 0; j < 4; ++j) acc[i][j] = (f32x4){0.f, 0.f, 0.f, 0.f};

    const short* bbase = WT + (size_t)(w * 64 + m) * 256 + q * 8;
    bf16x8 b[4];
#pragma unroll
    for (int j = 0; j < 4; ++j) b[j] = *(const bf16x8*)(bbase + (size_t)j * 4096);
#pragma unroll
    for (int kk = 0; kk < 8; ++kk) {
      bf16x8 bn[4];
      if (kk < 7) {
#pragma unroll
        for (int j = 0; j < 4; ++j) bn[j] = *(const bf16x8*)(bbase + (size_t)j * 4096 + (kk + 1) * 32);
      }
      bf16x8 a[4];
#pragma unroll
      for (int i = 0; i < 4; ++i) a[i] = *(const bf16x8*)&ax[(i * 16 + m) * 264 + kk * 32 + q * 8];
#pragma unroll
      for (int i = 0; i < 4; ++i)
#pragma unroll
        for (int j = 0; j < 4; ++j)
          acc[i][j] = __builtin_amdgcn_mfma_f32_16x16x32_bf16(a[i], b[j], acc[i][j], 0, 0, 0);
      if (kk < 7) {
#pragma unroll
        for (int j = 0; j < 4; ++j) b[j] = bn[j];
      }
    }
#pragma unroll
    for (int i = 0; i < 4; ++i)
#pragma unroll
      for (int j = 0; j < 4; ++j)
#pragma unroll
        for (int r = 0; r < 4; ++r) {
          size_t row = row0 + i * 16 + q * 4 + r;
          int col = w * 64 + j * 16 + m;
          O[row * 256 + col] = f2bf(acc[i][j][r]);
        }
  }
}

// ---------------- windowed attention (R6/R1 kernel, EXACT) ----------------
// HISTORY: this structure = VGPR 120, FETCH 31 MB, no spill (R1/R6/R9/R10).
// Every restructure (R2-R5 LDS overlay; R7 512-thread row-split) pushed
// natural register demand into the 129-150 band; the allocator clamps to the
// 128 occupancy step and spills sc[] IN-LOOP (~850 MB/dispatch scratch).
// DO NOT restructure this loop's register layout.
// SQ_LDS_BANK_CONFLICT = 3538944 = structural ds_read_b64 floor. Closed axis.
// NOTE: this kernel shows a bimodal environmental clock state: 60.1us @ 808
// GB/s or 131us @ 370 GB/s with IDENTICAL counters -- not code-dependent.
__global__ __launch_bounds__(256, 2) void attn_kernel(
    const short* __restrict__ XQb, const short* __restrict__ XKb, const short* __restrict__ XVb,
    const short* __restrict__ PQb, const short* __restrict__ PKb, const short* __restrict__ PVb,
    short* __restrict__ CTXB) {
  __shared__ short sq[RSN * SST];
  __shared__ short sk[RSN * SST];
  __shared__ short sv[RSN * SST];
  __shared__ short pq[WNN * SST];
  __shared__ short pk[WNN * SST];
  __shared__ short pv[WNN * SST];

  const int t = threadIdx.x;
  const int nblk = LL / CW;
  const int b = blockIdx.x / nblk;
  const int n0 = (blockIdx.x % nblk) * CW;
  const size_t base = (size_t)b * LL * DD;

  const int lq   = t & 63;
  const int gcol = ((((lq & 7) << 3) | (lq >> 3))) * 4;   // global short offset of this lane's short4
  const int pcol = ((lq >> 3) << 5) | ((lq & 7) << 2);    // physical LDS short offset

#pragma unroll
  for (int i = 0; i < RSN / 4; ++i) {   // 10 iters, one full row per wave
    int r = (t >> 6) + i * 4;
    int j = n0 - PPAD + r;
    short4 vq = {0, 0, 0, 0}, vk = vq, vv = vq;
    if (j >= 0 && j < LL) {
      size_t off = base + (size_t)j * DD + gcol;
      vq = *(const short4*)(XQb + off);
      vk = *(const short4*)(XKb + off);
      vv = *(const short4*)(XVb + off);
    }
    *(short4*)&sq[r * SST + pcol] = vq;
    *(short4*)&sk[r * SST + pcol] = vk;
    *(short4*)&sv[r * SST + pcol] = vv;
  }
#pragma unroll
  for (int i = 0; i < 3; ++i) {
    int r = (t >> 6) + i * 4;
    if (r < WNN) {
      *(short4*)&pq[r * SST + pcol] = *(const short4*)(PQb + r * DD + gcol);
      *(short4*)&pk[r * SST + pcol] = *(const short4*)(PKb + r * DD + gcol);
      *(short4*)&pv[r * SST + pcol] = *(const short4*)(PVb + r * DD + gcol);
    }
  }
  __syncthreads();

  const int n = t >> 3;        // window within block
  const int h = t & 7;         // head
  const int hoff = h * HDIM;   // logical head offset (used for global writes only)
  const int hph = h * 4;       // physical head offset within a 32-short chunk

  float sc[WNN][WNN];
#pragma unroll
  for (int qi = 0; qi < WNN; ++qi)
#pragma unroll
    for (int ki = 0; ki < WNN; ++ki) sc[qi][ki] = 0.f;

#pragma unroll
  for (int c = 0; c < 8; ++c) {
    const int cph = c * 32 + hph;
    float qv[WNN][4], kv[WNN][4];
#pragma unroll
    for (int r = 0; r < WNN; ++r) {
      short4 xa = *(const short4*)&sq[(n + r) * SST + cph];
      short4 pa = *(const short4*)&pq[r * SST + cph];
      qv[r][0] = bf2f(xa.x) + bf2f(pa.x);
      qv[r][1] = bf2f(xa.y) + bf2f(pa.y);
      qv[r][2] = bf2f(xa.z) + bf2f(pa.z);
      qv[r][3] = bf2f(xa.w) + bf2f(pa.w);
      short4 xb = *(const short4*)&sk[(n + r) * SST + cph];
      short4 pb = *(const short4*)&pk[r * SST + cph];
      kv[r][0] = bf2f(xb.x) + bf2f(pb.x);
      kv[r][1] = bf2f(xb.y) + bf2f(pb.y);
      kv[r][2] = bf2f(xb.z) + bf2f(pb.z);
      kv[r][3] = bf2f(xb.w) + bf2f(pb.w);
    }
#pragma unroll
    for (int qi = 0; qi < WNN; ++qi)
#pragma unroll
      for (int ki = 0; ki < WNN; ++ki)
        sc[qi][ki] += qv[qi][0] * kv[ki][0] + qv[qi][1] * kv[ki][1] +
                      qv[qi][2] * kv[ki][2] + qv[qi][3] * kv[ki][3];
  }

  float cs[WNN];
#pragma unroll
  for (int ki = 0; ki < WNN; ++ki) cs[ki] = 0.f;
  const float scale = 0.17677669529663687f;  // 1/sqrt(32)
#pragma unroll
  for (int qi = 0; qi < WNN; ++qi) {
    float mx = sc[qi][0];
#pragma unroll
    for (int ki = 1; ki < WNN; ++ki) mx = fmaxf(mx, sc[qi][ki]);
    float e[WNN], sum = 0.f;
#pragma unroll
    for (int ki = 0; ki < WNN; ++ki) { e[ki] = __expf((sc[qi][ki] - mx) * scale); sum += e[ki]; }
    float inv = 1.f / sum;
#pragma unroll
    for (int ki = 0; ki < WNN; ++ki) cs[ki] += e[ki] * inv;
  }

#pragma unroll
  for (int c = 0; c < 8; ++c) {
    const int cph = c * 32 + hph;
    float o0 = 0.f, o1 = 0.f, o2 = 0.f, o3 = 0.f;
#pragma unroll
    for (int ki = 0; ki < WNN; ++ki) {
      short4 xv4 = *(const short4*)&sv[(n + ki) * SST + cph];
      short4 pv4 = *(const short4*)&pv[ki * SST + cph];
      float wt = cs[ki];
      o0 += wt * (bf2f(xv4.x) + bf2f(pv4.x));
      o1 += wt * (bf2f(xv4.y) + bf2f(pv4.y));
      o2 += wt * (bf2f(xv4.z) + bf2f(pv4.z));
      o3 += wt * (bf2f(xv4.w) + bf2f(pv4.w));
    }
    short4 os; os.x = f2bf(o0); os.y = f2bf(o1); os.z = f2bf(o2); os.w = f2bf(o3);
    *(short4*)(CTXB + base + (size_t)(n0 + n) * DD + hoff + c * 4) = os;
  }
}

// CAUTION: softmax scale note — reference scales scores BEFORE softmax; we fold
// the scale into the exp argument ((sc-mx)*scale) which is equivalent since mx
// is the max of unscaled scores and scale>0.

// ---------------- fused out stage via MFMA (R10 exact: A staged in LDS) ----------------
__global__ __launch_bounds__(256) void out_mfma(
    const short* __restrict__ CTXB, const float* __restrict__ X,
    const short* __restrict__ WoT, const short* __restrict__ WoutB,
    const float* __restrict__ bo,
    const float* __restrict__ g1, const float* __restrict__ b1,
    const float* __restrict__ g2, const float* __restrict__ b2,
    float* __restrict__ out) {
  __shared__ short ar[64 * 264];
  __shared__ float ws1[64][4], ws2[64][4];
  __shared__ float msh[64], rsh[64];
  __shared__ float g1s[256], b1s[256], g2s[256], b2s[256], bos[256];
  const int t = threadIdx.x, w = t >> 6, lane = t & 63, q = lane >> 4, m = lane & 15;
  const size_t row0 = (size_t)blockIdx.x * 64;
  g1s[t] = g1[t]; b1s[t] = b1[t]; g2s[t] = g2[t]; b2s[t] = b2[t]; bos[t] = bo[t];

  // stage CTXB tile into ar (64 rows x 256 cols bf16)
#pragma unroll
  for (int i = 0; i < 16; ++i) {
    int idx = (i * 256 + t) * 4;        // flat short index in tile
    int row = idx >> 8, col = idx & 255;
    *(short4*)&ar[row * 264 + col] = *(const short4*)(CTXB + (row0 + row) * (size_t)256 + col);
  }
  __syncthreads();

  f32x4 acc[4][4];
#pragma unroll
  for (int i = 0; i < 4; ++i)
#pragma unroll
    for (int j = 0; j < 4; ++j) acc[i][j] = (f32x4){0.f, 0.f, 0.f, 0.f};

  // GEMM1: ctx @ Wo (A from LDS, B global with register-dbuf prefetch)
  const short* bbase = WoT + (size_t)(w * 64 + m) * 256 + q * 8;
  {
    bf16x8 b[4];
#pragma unroll
    for (int j = 0; j < 4; ++j) b[j] = *(const bf16x8*)(bbase + (size_t)j * 4096);
#pragma unroll
    for (int kk = 0; kk < 8; ++kk) {
      bf16x8 bn[4];
      if (kk < 7) {
#pragma unroll
        for (int j = 0; j < 4; ++j) bn[j] = *(const bf16x8*)(bbase + (size_t)j * 4096 + (kk + 1) * 32);
      }
      bf16x8 a[4];
#pragma unroll
      for (int i = 0; i < 4; ++i) a[i] = *(const bf16x8*)&ar[(i * 16 + m) * 264 + kk * 32 + q * 8];
#pragma unroll
      for (int i = 0; i < 4; ++i)
#pragma unroll
        for (int j = 0; j < 4; ++j)
          acc[i][j] = __builtin_amdgcn_mfma_f32_16x16x32_bf16(a[i], b[j], acc[i][j], 0, 0, 0);
      if (kk < 7) {
#pragma unroll
        for (int j = 0; j < 4; ++j) b[j] = bn[j];
      }
    }
  }

  // + skip, LN1 partial stats
  float s1v[4][4], s2v[4][4];
#pragma unroll
  for (int i = 0; i < 4; ++i)
#pragma unroll
    for (int r = 0; r < 4; ++r) {
      float a0 = 0.f, b0 = 0.f;
#pragma unroll
      for (int j = 0; j < 4; ++j) {
        float v = acc[i][j][r] + X[(row0 + i * 16 + q * 4 + r) * 256 + w * 64 + j * 16 + m];
        acc[i][j][r] = v; a0 += v; b0 += v * v;
      }
      s1v[i][r] = a0; s2v[i][r] = b0;
    }
#pragma unroll
  for (int i = 0; i < 4; ++i)
#pragma unroll
    for (int r = 0; r < 4; ++r)
#pragma unroll
      for (int msk = 1; msk < 16; msk <<= 1) {
        s1v[i][r] += __shfl_xor(s1v[i][r], msk, 64);
        s2v[i][r] += __shfl_xor(s2v[i][r], msk, 64);
      }
  if (m == 0) {
#pragma unroll
    for (int i = 0; i < 4; ++i)
#pragma unroll
      for (int r = 0; r < 4; ++r) {
        ws1[i * 16 + q * 4 + r][w] = s1v[i][r];
        ws2[i * 16 + q * 4 + r][w] = s2v[i][r];
      }
  }
  __syncthreads();
  if (t < 64) {
    float a0 = 0.f, b0 = 0.f;
#pragma unroll
    for (int ww = 0; ww < 4; ++ww) { a0 += ws1[t][ww]; b0 += ws2[t][ww]; }
    float mean = a0 * (1.f / 256.f);
    float var = b0 * (1.f / 256.f) - mean * mean;
    msh[t] = mean; rsh[t] = rsqrtf(var + 1e-5f);
  }
  __syncthreads();

#pragma unroll
  for (int i = 0; i < 4; ++i)
#pragma unroll
    for (int r = 0; r < 4; ++r) {
      int row = i * 16 + q * 4 + r;
      float mean = msh[row], rst = rsh[row];
#pragma unroll
      for (int j = 0; j < 4; ++j) {
        int col = w * 64 + j * 16 + m;
        float v = (acc[i][j][r] - mean) * rst * g1s[col] + b1s[col];
        ar[row * 264 + col] = f2bf(v);
      }
    }
  __syncthreads();

  // GEMM2: ar @ Wout^T (A from LDS, B global with prefetch)
#pragma unroll
  for (int i = 0; i < 4; ++i)
#pragma unroll
    for (int j = 0; j < 4; ++j) acc[i][j] = (f32x4){0.f, 0.f, 0.f, 0.f};
  const short* b2base = WoutB + (size_t)(w * 64 + m) * 256 + q * 8;
  {
    bf16x8 b[4];
#pragma unroll
    for (int j = 0; j < 4; ++j) b[j] = *(const bf16x8*)(b2base + (size_t)j * 4096);
#pragma unroll
    for (int kk = 0; kk < 8; ++kk) {
      bf16x8 bn[4];
      if (kk < 7) {
#pragma unroll
        for (int j = 0; j < 4; ++j) bn[j] = *(const bf16x8*)(b2base + (size_t)j * 4096 + (kk + 1) * 32);
      }
      bf16x8 a[4];
#pragma unroll
      for (int i = 0; i < 4; ++i) a[i] = *(const bf16x8*)&ar[(i * 16 + m) * 264 + kk * 32 + q * 8];
#pragma unroll
      for (int i = 0; i < 4; ++i)
#pragma unroll
        for (int j = 0; j < 4; ++j)
          acc[i][j] = __builtin_amdgcn_mfma_f32_16x16x32_bf16(a[i], b[j], acc[i][j], 0, 0, 0);
      if (kk < 7) {
#pragma unroll
        for (int j = 0; j < 4; ++j) b[j] = bn[j];
      }
    }
  }

  // + bias + residual, LN2 stats
#pragma unroll
  for (int i = 0; i < 4; ++i)
#pragma unroll
    for (int r = 0; r < 4; ++r) {
      int row = i * 16 + q * 4 + r;
      float a0 = 0.f, b0 = 0.f;
#pragma unroll
      for (int j = 0; j < 4; ++j) {
        int col = w * 64 + j * 16 + m;
        float v = acc[i][j][r] + bos[col] + bf2f(ar[row * 264 + col]);
        acc[i][j][r] = v; a0 += v; b0 += v * v;
      }
      s1v[i][r] = a0; s2v[i][r] = b0;
    }
#pragma unroll
  for (int i = 0; i < 4; ++i)
#pragma unroll
    for (int r = 0; r < 4; ++r)
#pragma unroll
      for (int msk = 1; msk < 16; msk <<= 1) {
        s1v[i][r] += __shfl_xor(s1v[i][r], msk, 64);
        s2v[i][r] += __shfl_xor(s2v[i][r], msk, 64);
      }
  if (m == 0) {
#pragma unroll
    for (int i = 0; i < 4; ++i)
#pragma unroll
      for (int r = 0; r < 4; ++r) {
        ws1[i * 16 + q * 4 + r][w] = s1v[i][r];
        ws2[i * 16 + q * 4 + r][w] = s2v[i][r];
      }
  }
  __syncthreads();
  if (t < 64) {
    float a0 = 0.f, b0 = 0.f;
#pragma unroll
    for (int ww = 0; ww < 4; ++ww) { a0 += ws1[t][ww]; b0 += ws2[t][ww]; }
    float mean = a0 * (1.f / 256.f);
    float var = b0 * (1.f / 256.f) - mean * mean;
    msh[t] = mean; rsh[t] = rsqrtf(var + 1e-5f);
  }
  __syncthreads();

#pragma unroll
  for (int i = 0; i < 4; ++i)
#pragma unroll
    for (int r = 0; r < 4; ++r) {
      int row = i * 16 + q * 4 + r;
      float mean = msh[row], rst = rsh[row];
#pragma unroll
      for (int j = 0; j < 4; ++j) {
        int col = w * 64 + j * 16 + m;
        float v = (acc[i][j][r] - mean) * rst * g2s[col] + b2s[col];
        out[(row0 + row) * 256 + col] = fmaxf(v, 0.f);
      }
    }
}

extern "C" void kernel_launch(void* const* d_in, const int* in_sizes, int n_in,
                              void* d_out, int out_size, void* d_ws, size_t ws_size,
                              hipStream_t stream) {
  const float* x    = (const float*)d_in[0];
  const float* Wq   = (const float*)d_in[1];
  const float* Wk   = (const float*)d_in[2];
  const float* Wv   = (const float*)d_in[3];
  const float* Wo   = (const float*)d_in[4];
  const float* pos  = (const float*)d_in[5];
  const float* Wout = (const float*)d_in[6];
  const float* bo   = (const float*)d_in[7];
  const float* g1   = (const float*)d_in[8];
  const float* b1   = (const float*)d_in[9];
  const float* g2   = (const float*)d_in[10];
  const float* b2   = (const float*)d_in[11];
  float* out = (float*)d_out;

  const size_t nel = (size_t)NB * LL * DD;
  char* wsb = (char*)d_ws;
  short* XQb  = (short*)wsb; wsb += nel * 2;
  short* XKb  = (short*)wsb; wsb += nel * 2;
  short* XVb  = (short*)wsb; wsb += nel * 2;
  short* CTXB = (short*)wsb; wsb += nel * 2;
  short* WqT   = (short*)wsb; wsb += 65536 * 2;
  short* WkT   = (short*)wsb; wsb += 65536 * 2;
  short* WvT   = (short*)wsb; wsb += 65536 * 2;
  short* WoT   = (short*)wsb; wsb += 65536 * 2;
  short* WoutB = (short*)wsb; wsb += 65536 * 2;
  short* PQb = (short*)wsb; wsb += WNN * DD * 2;
  short* PKb = (short*)wsb; wsb += WNN * DD * 2;
  short* PVb = (short*)wsb; wsb += WNN * DD * 2;

  prep_all<<<32, 256, 0, stream>>>(
      Wq, Wk, Wv, Wo, Wout, WqT, WkT, WvT, WoT, WoutB, pos, PQb, PKb, PVb);
  qkv_mfma<<<(unsigned)(NB * LL / 64), 256, 0, stream>>>(x, WqT, WkT, WvT, XQb, XKb, XVb);
  attn_kernel<<<NB * (LL / CW), 256, 0, stream>>>(XQb, XKb, XVb, PQb, PKb, PVb, CTXB);
  out_mfma<<<(unsigned)(NB * LL / 64), 256, 0, stream>>>(CTXB, x, WoT, WoutB, bo, g1, b1, g2, b2, out);
}